// Round 1
// baseline (1369.179 us; speedup 1.0000x reference)
//
#include <hip/hip_runtime.h>

#define NN 100000
#define EE 3200000
#define BB 128

// ---------------- setup kernels ----------------

__global__ void k_init(int* __restrict__ deg, int* __restrict__ bstart, int* __restrict__ bend) {
  int i = blockIdx.x * 256 + threadIdx.x;
  if (i < NN) deg[i] = 1;                 // self-loop contributes 1
  if (i < BB) { bstart[i] = NN; bend[i] = 0; }
}

__global__ void k_count(const int* __restrict__ ei, int* __restrict__ deg) {
  int e = blockIdx.x * 256 + threadIdx.x;
  if (e < EE) atomicAdd(&deg[ei[EE + e]], 1);
}

// ---- exclusive scan of deg -> row_start (chunk = 1024 elems / block) ----

__global__ void k_scan1(const int* __restrict__ deg, int* __restrict__ bsum) {
  int t = threadIdx.x;
  int base = blockIdx.x * 1024 + t * 4;
  int s = 0;
#pragma unroll
  for (int j = 0; j < 4; j++) { int idx = base + j; if (idx < NN) s += deg[idx]; }
  __shared__ int red[256];
  red[t] = s; __syncthreads();
  for (int off = 128; off > 0; off >>= 1) { if (t < off) red[t] += red[t + off]; __syncthreads(); }
  if (t == 0) bsum[blockIdx.x] = red[0];
}

__global__ void k_scan2(const int* __restrict__ bsum, int* __restrict__ bpre, int nb,
                        int* __restrict__ row_start) {
  if (threadIdx.x == 0 && blockIdx.x == 0) {
    int run = 0;
    for (int i = 0; i < nb; i++) { bpre[i] = run; run += bsum[i]; }
    row_start[NN] = run;  // == EE + NN
  }
}

__global__ void k_scan3(const int* __restrict__ deg, const int* __restrict__ bpre,
                        int* __restrict__ row_start) {
  int t = threadIdx.x;
  int base = blockIdx.x * 1024 + t * 4;
  int v[4]; int local = 0;
#pragma unroll
  for (int j = 0; j < 4; j++) { int idx = base + j; v[j] = (idx < NN) ? deg[idx] : 0; local += v[j]; }
  __shared__ int tmp[256];
  tmp[t] = local; __syncthreads();
  for (int off = 1; off < 256; off <<= 1) {
    int u = (t >= off) ? tmp[t - off] : 0;
    __syncthreads();
    tmp[t] += u;
    __syncthreads();
  }
  int run = bpre[blockIdx.x] + tmp[t] - local;  // exclusive prefix for this thread's 4
#pragma unroll
  for (int j = 0; j < 4; j++) { int idx = base + j; if (idx < NN) { row_start[idx] = run; run += v[j]; } }
}

__global__ void k_dis_cursor(const int* __restrict__ deg, const int* __restrict__ row_start,
                             float* __restrict__ dis, int* __restrict__ cursor) {
  int i = blockIdx.x * 256 + threadIdx.x;
  if (i < NN) { dis[i] = rsqrtf((float)deg[i]); cursor[i] = row_start[i]; }
}

__global__ void k_fill(const int* __restrict__ ei, int* __restrict__ cursor,
                       int* __restrict__ srcs) {
  int t = blockIdx.x * 256 + threadIdx.x;
  if (t >= EE + NN) return;
  int s, d;
  if (t < EE) { s = ei[t]; d = ei[EE + t]; }
  else        { s = t - EE; d = s; }            // self-loops
  int pos = atomicAdd(&cursor[d], 1);
  srcs[pos] = s;
}

__global__ void k_bounds(const int* __restrict__ batch, int* __restrict__ bstart,
                         int* __restrict__ bend) {
  int i = blockIdx.x * 256 + threadIdx.x;
  if (i < NN) { int b = batch[i]; atomicMin(&bstart[b], i); atomicMax(&bend[b], i + 1); }
}

// ---------------- matmul: out[r][c] = dis[r] * sum_k in[r][k] W[k][c] ----------------
// 256 thr/block, 64 rows x 64 cols per block; thread = 4 rows x 4 cols register tile.
// K staged in 64-wide halves so static LDS stays < 64 KB for CIN=128.

template <int CIN>
__global__ __launch_bounds__(256) void k_matmul_scale(
    const float* __restrict__ in, const float* __restrict__ W,
    const float* __restrict__ dis, float* __restrict__ out) {
  __shared__ float Wl[CIN * 64];
  __shared__ float xr[64 * 68];   // 64 rows x 64 k-cols, stride 68 (bank-spread, 16B aligned)
  int t = threadIdx.x;
  for (int i = t * 4; i < CIN * 64; i += 1024)
    *(float4*)&Wl[i] = *(const float4*)&W[i];

  int base = blockIdx.x * 64;
  int rows = NN - base; if (rows > 64) rows = 64;

  int cg = t & 15, rg = t >> 4;
  int c0 = cg * 4;
  float acc[4][4] = {};

  for (int kh = 0; kh < CIN; kh += 64) {
    // stage x[base..base+rows)[kh..kh+64) into xr
    for (int i = t * 4; i < rows * 64; i += 1024) {
      int r = i >> 6, c = i & 63;
      *(float4*)&xr[r * 68 + c] = *(const float4*)&in[(base + r) * CIN + kh + c];
    }
    __syncthreads();
#pragma unroll
    for (int kl = 0; kl < 64; kl += 4) {
      float4 xv[4], wv[4];
#pragma unroll
      for (int j = 0; j < 4; j++) xv[j] = *(float4*)&xr[(rg * 4 + j) * 68 + kl];
#pragma unroll
      for (int kk = 0; kk < 4; kk++) wv[kk] = *(float4*)&Wl[(kh + kl + kk) * 64 + c0];
#pragma unroll
      for (int kk = 0; kk < 4; kk++) {
#pragma unroll
        for (int j = 0; j < 4; j++) {
          float xs = (&xv[j].x)[kk];
          acc[j][0] += xs * wv[kk].x;
          acc[j][1] += xs * wv[kk].y;
          acc[j][2] += xs * wv[kk].z;
          acc[j][3] += xs * wv[kk].w;
        }
      }
    }
    __syncthreads();
  }

#pragma unroll
  for (int j = 0; j < 4; j++) {
    int r = base + rg * 4 + j;
    if (r < NN) {
      float dv = dis[r];
      float4 o; o.x = acc[j][0] * dv; o.y = acc[j][1] * dv; o.z = acc[j][2] * dv; o.w = acc[j][3] * dv;
      *(float4*)&out[r * 64 + c0] = o;
    }
  }
}

// ---------------- aggregation: one wave per node, lane = channel ----------------
// out[i][lane] = relu(dis[i] * sum_{e in CSR(i)} tp[src_e][lane] + bias[lane])

__global__ __launch_bounds__(256) void k_agg(
    const float* __restrict__ tp, const int* __restrict__ row_start,
    const int* __restrict__ srcs, const float* __restrict__ dis,
    const float* __restrict__ bias, float* __restrict__ out) {
  int wid = (blockIdx.x * 256 + threadIdx.x) >> 6;
  int lane = threadIdx.x & 63;
  if (wid >= NN) return;
  int s = row_start[wid], e = row_start[wid + 1];
  float a0 = 0.f, a1 = 0.f, a2 = 0.f, a3 = 0.f;
  int p = s;
  for (; p + 4 <= e; p += 4) {
    int s0 = srcs[p], s1 = srcs[p + 1], s2 = srcs[p + 2], s3 = srcs[p + 3];
    a0 += tp[s0 * 64 + lane];
    a1 += tp[s1 * 64 + lane];
    a2 += tp[s2 * 64 + lane];
    a3 += tp[s3 * 64 + lane];
  }
  for (; p < e; ++p) a0 += tp[srcs[p] * 64 + lane];
  float acc = (a0 + a1) + (a2 + a3);
  float r = acc * dis[wid] + bias[lane];
  out[wid * 64 + lane] = fmaxf(r, 0.f);
}

// ---------------- fused mean-pool + 2-layer MLP ----------------

__global__ __launch_bounds__(256) void k_pool_mlp(
    const float* __restrict__ h, const int* __restrict__ bstart, const int* __restrict__ bend,
    const float* __restrict__ Wm1, const float* __restrict__ bm1,
    const float* __restrict__ Wm2, const float* __restrict__ bm2,
    float* __restrict__ out) {
  int b = blockIdx.x;
  int t = threadIdx.x;
  int lane = t & 63, w = t >> 6;
  int s = bstart[b], e = bend[b];
  float acc = 0.f;
  for (int i = s + w; i < e; i += 4) acc += h[i * 64 + lane];
  __shared__ float sums[4][64];
  __shared__ float pooled[64];
  sums[w][lane] = acc;
  __syncthreads();
  if (t < 64) {
    float tot = sums[0][t] + sums[1][t] + sums[2][t] + sums[3][t];
    int cnt = e - s;                       // empty batch -> negative, clamped below
    pooled[t] = tot / fmaxf((float)cnt, 1.0f);
  }
  __syncthreads();
  if (t < 32) {
    float z = bm1[t];
#pragma unroll
    for (int c = 0; c < 64; c++) z += pooled[c] * Wm1[c * 32 + t];
    z = fmaxf(z, 0.f) * Wm2[t];
#pragma unroll
    for (int off = 16; off > 0; off >>= 1) z += __shfl_down(z, off, 32);
    if (t == 0) out[b] = z + bm2[0];
  }
}

// ---------------- launch ----------------

extern "C" void kernel_launch(void* const* d_in, const int* in_sizes, int n_in,
                              void* d_out, int out_size, void* d_ws, size_t ws_size,
                              hipStream_t stream) {
  const float* x   = (const float*)d_in[0];
  const int*   ei  = (const int*)d_in[1];
  const int*   bat = (const int*)d_in[2];
  const float* W0  = (const float*)d_in[3];
  const float* b0  = (const float*)d_in[4];
  const float* W1  = (const float*)d_in[5];
  const float* b1  = (const float*)d_in[6];
  const float* W2  = (const float*)d_in[7];
  const float* b2  = (const float*)d_in[8];
  const float* Wm1 = (const float*)d_in[9];
  const float* bm1 = (const float*)d_in[10];
  const float* Wm2 = (const float*)d_in[11];
  const float* bm2 = (const float*)d_in[12];
  float* out = (float*)d_out;

  char* ws = (char*)d_ws;
  size_t off = 0;
  auto alloc = [&](size_t bytes) -> void* {
    void* p = ws + off; off += (bytes + 255) & ~(size_t)255; return p;
  };
  int*   deg  = (int*)  alloc((size_t)NN * 4);
  float* dis  = (float*)alloc((size_t)NN * 4);
  int*   rs   = (int*)  alloc((size_t)(NN + 1) * 4);
  int*   cur  = (int*)  alloc((size_t)NN * 4);
  int*   srcs = (int*)  alloc((size_t)(EE + NN) * 4);
  float* hA   = (float*)alloc((size_t)NN * 64 * 4);
  float* hB   = (float*)alloc((size_t)NN * 64 * 4);
  int*   bsum = (int*)  alloc(128 * 4);
  int*   bpre = (int*)  alloc(128 * 4);
  int*   bst  = (int*)  alloc(BB * 4);
  int*   ben  = (int*)  alloc(BB * 4);

  const int nb = (NN + 1023) / 1024;      // 98

  k_init<<<(NN + 255) / 256, 256, 0, stream>>>(deg, bst, ben);
  k_count<<<(EE + 255) / 256, 256, 0, stream>>>(ei, deg);
  k_scan1<<<nb, 256, 0, stream>>>(deg, bsum);
  k_scan2<<<1, 64, 0, stream>>>(bsum, bpre, nb, rs);
  k_scan3<<<nb, 256, 0, stream>>>(deg, bpre, rs);
  k_dis_cursor<<<(NN + 255) / 256, 256, 0, stream>>>(deg, rs, dis, cur);
  k_fill<<<(EE + NN + 255) / 256, 256, 0, stream>>>(ei, cur, srcs);
  k_bounds<<<(NN + 255) / 256, 256, 0, stream>>>(bat, bst, ben);

  const int mmgrid = (NN + 63) / 64;      // 1563

  k_matmul_scale<128><<<mmgrid, 256, 0, stream>>>(x,  W0, dis, hA);
  k_agg<<<(NN + 3) / 4, 256, 0, stream>>>(hA, rs, srcs, dis, b0, hB);

  k_matmul_scale<64><<<mmgrid, 256, 0, stream>>>(hB, W1, dis, hA);
  k_agg<<<(NN + 3) / 4, 256, 0, stream>>>(hA, rs, srcs, dis, b1, hB);

  k_matmul_scale<64><<<mmgrid, 256, 0, stream>>>(hB, W2, dis, hA);
  k_agg<<<(NN + 3) / 4, 256, 0, stream>>>(hA, rs, srcs, dis, b2, hB);

  k_pool_mlp<<<BB, 256, 0, stream>>>(hB, bst, ben, Wm1, bm1, Wm2, bm2, out);
}

// Round 2
// 1042.725 us; speedup vs baseline: 1.3131x; 1.3131x over previous
//
#include <hip/hip_runtime.h>

#define NN 100000
#define EE 3200000
#define BB 128

// ---------------- setup kernels ----------------

__global__ void k_init(int* __restrict__ deg, int* __restrict__ bstart, int* __restrict__ bend) {
  int i = blockIdx.x * 256 + threadIdx.x;
  if (i < NN) deg[i] = 1;                 // self-loop contributes 1
  if (i < BB) { bstart[i] = 0; bend[i] = 0; }
}

__global__ void k_count(const int* __restrict__ ei, int* __restrict__ deg) {
  int e = blockIdx.x * 256 + threadIdx.x;
  if (e < EE) atomicAdd(&deg[ei[EE + e]], 1);
}

// ---- exclusive scan of deg -> row_start (chunk = 1024 elems / block) ----

__global__ void k_scan1(const int* __restrict__ deg, int* __restrict__ bsum) {
  int t = threadIdx.x;
  int base = blockIdx.x * 1024 + t * 4;
  int s = 0;
#pragma unroll
  for (int j = 0; j < 4; j++) { int idx = base + j; if (idx < NN) s += deg[idx]; }
  __shared__ int red[256];
  red[t] = s; __syncthreads();
  for (int off = 128; off > 0; off >>= 1) { if (t < off) red[t] += red[t + off]; __syncthreads(); }
  if (t == 0) bsum[blockIdx.x] = red[0];
}

__global__ void k_scan2(const int* __restrict__ bsum, int* __restrict__ bpre, int nb,
                        int* __restrict__ row_start) {
  if (threadIdx.x == 0 && blockIdx.x == 0) {
    int run = 0;
    for (int i = 0; i < nb; i++) { bpre[i] = run; run += bsum[i]; }
    row_start[NN] = run;  // == EE + NN
  }
}

__global__ void k_scan3(const int* __restrict__ deg, const int* __restrict__ bpre,
                        int* __restrict__ row_start) {
  int t = threadIdx.x;
  int base = blockIdx.x * 1024 + t * 4;
  int v[4]; int local = 0;
#pragma unroll
  for (int j = 0; j < 4; j++) { int idx = base + j; v[j] = (idx < NN) ? deg[idx] : 0; local += v[j]; }
  __shared__ int tmp[256];
  tmp[t] = local; __syncthreads();
  for (int off = 1; off < 256; off <<= 1) {
    int u = (t >= off) ? tmp[t - off] : 0;
    __syncthreads();
    tmp[t] += u;
    __syncthreads();
  }
  int run = bpre[blockIdx.x] + tmp[t] - local;  // exclusive prefix for this thread's 4
#pragma unroll
  for (int j = 0; j < 4; j++) { int idx = base + j; if (idx < NN) { row_start[idx] = run; run += v[j]; } }
}

__global__ void k_dis_cursor(const int* __restrict__ deg, const int* __restrict__ row_start,
                             float* __restrict__ dis, int* __restrict__ cursor) {
  int i = blockIdx.x * 256 + threadIdx.x;
  if (i < NN) { dis[i] = rsqrtf((float)deg[i]); cursor[i] = row_start[i]; }
}

__global__ void k_fill(const int* __restrict__ ei, int* __restrict__ cursor,
                       int* __restrict__ srcs) {
  int t = blockIdx.x * 256 + threadIdx.x;
  if (t >= EE + NN) return;
  int s, d;
  if (t < EE) { s = ei[t]; d = ei[EE + t]; }
  else        { s = t - EE; d = s; }            // self-loops
  int pos = atomicAdd(&cursor[d], 1);
  srcs[pos] = s;
}

// batch is SORTED -> segment boundaries via adjacent compare; zero atomics.
__global__ void k_bounds(const int* __restrict__ batch, int* __restrict__ bstart,
                         int* __restrict__ bend) {
  int i = blockIdx.x * 256 + threadIdx.x;
  if (i >= NN) return;
  int b = batch[i];
  if (i == 0 || batch[i - 1] != b) bstart[b] = i;
  if (i == NN - 1 || batch[i + 1] != b) bend[b] = i + 1;
}

// ---------------- matmul: out[r][c] = dis[r] * sum_k in[r][k] W[k][c] ----------------
// 256 thr/block, 64 rows x 64 cols per block; thread = 4 rows x 4 cols register tile.
// K staged in 64-wide halves so static LDS stays < 64 KB for CIN=128.

template <int CIN>
__global__ __launch_bounds__(256) void k_matmul_scale(
    const float* __restrict__ in, const float* __restrict__ W,
    const float* __restrict__ dis, float* __restrict__ out) {
  __shared__ float Wl[CIN * 64];
  __shared__ float xr[64 * 68];   // 64 rows x 64 k-cols, stride 68 (bank-spread, 16B aligned)
  int t = threadIdx.x;
  for (int i = t * 4; i < CIN * 64; i += 1024)
    *(float4*)&Wl[i] = *(const float4*)&W[i];

  int base = blockIdx.x * 64;
  int rows = NN - base; if (rows > 64) rows = 64;

  int cg = t & 15, rg = t >> 4;
  int c0 = cg * 4;
  float acc[4][4] = {};

  for (int kh = 0; kh < CIN; kh += 64) {
    // stage x[base..base+rows)[kh..kh+64) into xr
    for (int i = t * 4; i < rows * 64; i += 1024) {
      int r = i >> 6, c = i & 63;
      *(float4*)&xr[r * 68 + c] = *(const float4*)&in[(base + r) * CIN + kh + c];
    }
    __syncthreads();
#pragma unroll
    for (int kl = 0; kl < 64; kl += 4) {
      float4 xv[4], wv[4];
#pragma unroll
      for (int j = 0; j < 4; j++) xv[j] = *(float4*)&xr[(rg * 4 + j) * 68 + kl];
#pragma unroll
      for (int kk = 0; kk < 4; kk++) wv[kk] = *(float4*)&Wl[(kh + kl + kk) * 64 + c0];
#pragma unroll
      for (int kk = 0; kk < 4; kk++) {
#pragma unroll
        for (int j = 0; j < 4; j++) {
          float xs = (&xv[j].x)[kk];
          acc[j][0] += xs * wv[kk].x;
          acc[j][1] += xs * wv[kk].y;
          acc[j][2] += xs * wv[kk].z;
          acc[j][3] += xs * wv[kk].w;
        }
      }
    }
    __syncthreads();
  }

#pragma unroll
  for (int j = 0; j < 4; j++) {
    int r = base + rg * 4 + j;
    if (r < NN) {
      float dv = dis[r];
      float4 o; o.x = acc[j][0] * dv; o.y = acc[j][1] * dv; o.z = acc[j][2] * dv; o.w = acc[j][3] * dv;
      *(float4*)&out[r * 64 + c0] = o;
    }
  }
}

// ---------------- aggregation: one wave per node, lane = channel ----------------
// out[i][lane] = relu(dis[i] * sum_{e in CSR(i)} tp[src_e][lane] + bias[lane])

__global__ __launch_bounds__(256) void k_agg(
    const float* __restrict__ tp, const int* __restrict__ row_start,
    const int* __restrict__ srcs, const float* __restrict__ dis,
    const float* __restrict__ bias, float* __restrict__ out) {
  int wid = (blockIdx.x * 256 + threadIdx.x) >> 6;
  int lane = threadIdx.x & 63;
  if (wid >= NN) return;
  int s = row_start[wid], e = row_start[wid + 1];
  float a0 = 0.f, a1 = 0.f, a2 = 0.f, a3 = 0.f;
  int p = s;
  for (; p + 4 <= e; p += 4) {
    int s0 = srcs[p], s1 = srcs[p + 1], s2 = srcs[p + 2], s3 = srcs[p + 3];
    a0 += tp[s0 * 64 + lane];
    a1 += tp[s1 * 64 + lane];
    a2 += tp[s2 * 64 + lane];
    a3 += tp[s3 * 64 + lane];
  }
  for (; p < e; ++p) a0 += tp[srcs[p] * 64 + lane];
  float acc = (a0 + a1) + (a2 + a3);
  float r = acc * dis[wid] + bias[lane];
  out[wid * 64 + lane] = fmaxf(r, 0.f);
}

// ---------------- fused mean-pool + 2-layer MLP ----------------

__global__ __launch_bounds__(256) void k_pool_mlp(
    const float* __restrict__ h, const int* __restrict__ bstart, const int* __restrict__ bend,
    const float* __restrict__ Wm1, const float* __restrict__ bm1,
    const float* __restrict__ Wm2, const float* __restrict__ bm2,
    float* __restrict__ out) {
  int b = blockIdx.x;
  int t = threadIdx.x;
  int lane = t & 63, w = t >> 6;
  int s = bstart[b], e = bend[b];
  float acc = 0.f;
  for (int i = s + w; i < e; i += 4) acc += h[i * 64 + lane];
  __shared__ float sums[4][64];
  __shared__ float pooled[64];
  sums[w][lane] = acc;
  __syncthreads();
  if (t < 64) {
    float tot = sums[0][t] + sums[1][t] + sums[2][t] + sums[3][t];
    int cnt = e - s;                       // empty batch -> 0, clamped below
    pooled[t] = tot / fmaxf((float)cnt, 1.0f);
  }
  __syncthreads();
  if (t < 32) {
    float z = bm1[t];
#pragma unroll
    for (int c = 0; c < 64; c++) z += pooled[c] * Wm1[c * 32 + t];
    z = fmaxf(z, 0.f) * Wm2[t];
#pragma unroll
    for (int off = 16; off > 0; off >>= 1) z += __shfl_down(z, off, 32);
    if (t == 0) out[b] = z + bm2[0];
  }
}

// ---------------- launch ----------------

extern "C" void kernel_launch(void* const* d_in, const int* in_sizes, int n_in,
                              void* d_out, int out_size, void* d_ws, size_t ws_size,
                              hipStream_t stream) {
  const float* x   = (const float*)d_in[0];
  const int*   ei  = (const int*)d_in[1];
  const int*   bat = (const int*)d_in[2];
  const float* W0  = (const float*)d_in[3];
  const float* b0  = (const float*)d_in[4];
  const float* W1  = (const float*)d_in[5];
  const float* b1  = (const float*)d_in[6];
  const float* W2  = (const float*)d_in[7];
  const float* b2  = (const float*)d_in[8];
  const float* Wm1 = (const float*)d_in[9];
  const float* bm1 = (const float*)d_in[10];
  const float* Wm2 = (const float*)d_in[11];
  const float* bm2 = (const float*)d_in[12];
  float* out = (float*)d_out;

  char* ws = (char*)d_ws;
  size_t off = 0;
  auto alloc = [&](size_t bytes) -> void* {
    void* p = ws + off; off += (bytes + 255) & ~(size_t)255; return p;
  };
  int*   deg  = (int*)  alloc((size_t)NN * 4);
  float* dis  = (float*)alloc((size_t)NN * 4);
  int*   rs   = (int*)  alloc((size_t)(NN + 1) * 4);
  int*   cur  = (int*)  alloc((size_t)NN * 4);
  int*   srcs = (int*)  alloc((size_t)(EE + NN) * 4);
  float* hA   = (float*)alloc((size_t)NN * 64 * 4);
  float* hB   = (float*)alloc((size_t)NN * 64 * 4);
  int*   bsum = (int*)  alloc(128 * 4);
  int*   bpre = (int*)  alloc(128 * 4);
  int*   bst  = (int*)  alloc(BB * 4);
  int*   ben  = (int*)  alloc(BB * 4);

  const int nb = (NN + 1023) / 1024;      // 98

  k_init<<<(NN + 255) / 256, 256, 0, stream>>>(deg, bst, ben);
  k_count<<<(EE + 255) / 256, 256, 0, stream>>>(ei, deg);
  k_scan1<<<nb, 256, 0, stream>>>(deg, bsum);
  k_scan2<<<1, 64, 0, stream>>>(bsum, bpre, nb, rs);
  k_scan3<<<nb, 256, 0, stream>>>(deg, bpre, rs);
  k_dis_cursor<<<(NN + 255) / 256, 256, 0, stream>>>(deg, rs, dis, cur);
  k_fill<<<(EE + NN + 255) / 256, 256, 0, stream>>>(ei, cur, srcs);
  k_bounds<<<(NN + 255) / 256, 256, 0, stream>>>(bat, bst, ben);

  const int mmgrid = (NN + 63) / 64;      // 1563

  k_matmul_scale<128><<<mmgrid, 256, 0, stream>>>(x,  W0, dis, hA);
  k_agg<<<(NN + 3) / 4, 256, 0, stream>>>(hA, rs, srcs, dis, b0, hB);

  k_matmul_scale<64><<<mmgrid, 256, 0, stream>>>(hB, W1, dis, hA);
  k_agg<<<(NN + 3) / 4, 256, 0, stream>>>(hA, rs, srcs, dis, b1, hB);

  k_matmul_scale<64><<<mmgrid, 256, 0, stream>>>(hB, W2, dis, hA);
  k_agg<<<(NN + 3) / 4, 256, 0, stream>>>(hA, rs, srcs, dis, b2, hB);

  k_pool_mlp<<<BB, 256, 0, stream>>>(hB, bst, ben, Wm1, bm1, Wm2, bm2, out);
}

// Round 3
// 863.607 us; speedup vs baseline: 1.5854x; 1.2074x over previous
//
#include <hip/hip_runtime.h>

#define NN 100000
#define EE 3200000
#define BB 128
#define MM (EE + NN)            // edges incl. self-loops
#define NBK 391                 // buckets of 256 nodes: (NN+255)/256
#define CHUNK 8192
#define NCH ((MM + CHUNK - 1) / CHUNK)   // 403

// ---------------- setup kernels ----------------

__global__ void k_init(int* __restrict__ deg, int* __restrict__ bstart, int* __restrict__ bend,
                       int* __restrict__ gcnt) {
  int i = blockIdx.x * 256 + threadIdx.x;
  if (i < NN) deg[i] = 0;                 // self-loops counted via bucketed stream
  if (i < BB) { bstart[i] = 0; bend[i] = 0; }
  if (i < NBK) gcnt[i] = 0;
}

// per-block LDS histogram of dst buckets -> global bucket counts
__global__ __launch_bounds__(256) void k_hist(const int* __restrict__ ei, int* __restrict__ gcnt) {
  __shared__ int lh[NBK];
  int t = threadIdx.x;
  for (int b = t; b < NBK; b += 256) lh[b] = 0;
  __syncthreads();
  int base = blockIdx.x * CHUNK;
  for (int i = t; i < CHUNK; i += 256) {
    int e = base + i; if (e >= MM) break;
    int d = (e < EE) ? ei[EE + e] : (e - EE);
    atomicAdd(&lh[d >> 8], 1);
  }
  __syncthreads();
  for (int b = t; b < NBK; b += 256) { int c = lh[b]; if (c) atomicAdd(&gcnt[b], c); }
}

// exclusive scan of 391 bucket counts -> bucket cursors (one 512-thread block)
__global__ void k_bscan(const int* __restrict__ gcnt, int* __restrict__ curB) {
  __shared__ int sc[512];
  int t = threadIdx.x;
  int v = (t < NBK) ? gcnt[t] : 0;
  sc[t] = v; __syncthreads();
  for (int off = 1; off < 512; off <<= 1) {
    int u = (t >= off) ? sc[t - off] : 0;
    __syncthreads();
    sc[t] += u;
    __syncthreads();
  }
  if (t < NBK) curB[t] = sc[t] - v;     // exclusive prefix
}

// scatter edges into bucket-sorted int2 array (src,dst); coalesced-ish writes
__global__ __launch_bounds__(256) void k_scatter(const int* __restrict__ ei,
                                                 int* __restrict__ curB, int2* __restrict__ bkt) {
  __shared__ int lh[NBK];
  __shared__ int lbase[NBK];
  int t = threadIdx.x;
  for (int b = t; b < NBK; b += 256) lh[b] = 0;
  __syncthreads();
  int base = blockIdx.x * CHUNK;
  for (int i = t; i < CHUNK; i += 256) {
    int e = base + i; if (e >= MM) break;
    int d = (e < EE) ? ei[EE + e] : (e - EE);
    atomicAdd(&lh[d >> 8], 1);
  }
  __syncthreads();
  for (int b = t; b < NBK; b += 256) {
    int c = lh[b];
    lbase[b] = c ? atomicAdd(&curB[b], c) : 0;
    lh[b] = 0;
  }
  __syncthreads();
  for (int i = t; i < CHUNK; i += 256) {
    int e = base + i; if (e >= MM) break;
    int s, d;
    if (e < EE) { s = ei[e]; d = ei[EE + e]; } else { s = e - EE; d = s; }
    int b = d >> 8;
    int r = atomicAdd(&lh[b], 1);
    bkt[lbase[b] + r] = make_int2(s, d);
  }
}

// count per-node degree from bucketed stream (atomics localized to 1KB windows)
__global__ void k_count2(const int2* __restrict__ bkt, int* __restrict__ deg) {
  int i = blockIdx.x * 256 + threadIdx.x;
  if (i < MM) { int2 v = bkt[i]; atomicAdd(&deg[v.y], 1); }
}

// ---- exclusive scan of deg -> row_start (chunk = 1024 elems / block) ----

__global__ void k_scan1(const int* __restrict__ deg, int* __restrict__ bsum) {
  int t = threadIdx.x;
  int base = blockIdx.x * 1024 + t * 4;
  int s = 0;
#pragma unroll
  for (int j = 0; j < 4; j++) { int idx = base + j; if (idx < NN) s += deg[idx]; }
  __shared__ int red[256];
  red[t] = s; __syncthreads();
  for (int off = 128; off > 0; off >>= 1) { if (t < off) red[t] += red[t + off]; __syncthreads(); }
  if (t == 0) bsum[blockIdx.x] = red[0];
}

__global__ void k_scan2(const int* __restrict__ bsum, int* __restrict__ bpre, int nb,
                        int* __restrict__ row_start) {
  if (threadIdx.x == 0 && blockIdx.x == 0) {
    int run = 0;
    for (int i = 0; i < nb; i++) { bpre[i] = run; run += bsum[i]; }
    row_start[NN] = run;  // == MM
  }
}

__global__ void k_scan3(const int* __restrict__ deg, const int* __restrict__ bpre,
                        int* __restrict__ row_start) {
  int t = threadIdx.x;
  int base = blockIdx.x * 1024 + t * 4;
  int v[4]; int local = 0;
#pragma unroll
  for (int j = 0; j < 4; j++) { int idx = base + j; v[j] = (idx < NN) ? deg[idx] : 0; local += v[j]; }
  __shared__ int tmp[256];
  tmp[t] = local; __syncthreads();
  for (int off = 1; off < 256; off <<= 1) {
    int u = (t >= off) ? tmp[t - off] : 0;
    __syncthreads();
    tmp[t] += u;
    __syncthreads();
  }
  int run = bpre[blockIdx.x] + tmp[t] - local;  // exclusive prefix for this thread's 4
#pragma unroll
  for (int j = 0; j < 4; j++) { int idx = base + j; if (idx < NN) { row_start[idx] = run; run += v[j]; } }
}

__global__ void k_dis_cursor(const int* __restrict__ deg, const int* __restrict__ row_start,
                             float* __restrict__ dis, int* __restrict__ cursor) {
  int i = blockIdx.x * 256 + threadIdx.x;
  if (i < NN) { dis[i] = rsqrtf((float)deg[i]); cursor[i] = row_start[i]; }
}

// fill CSR srcs from bucketed stream (writes localized to ~33KB windows)
__global__ void k_fill2(const int2* __restrict__ bkt, int* __restrict__ cursor,
                        int* __restrict__ srcs) {
  int i = blockIdx.x * 256 + threadIdx.x;
  if (i < MM) { int2 v = bkt[i]; int pos = atomicAdd(&cursor[v.y], 1); srcs[pos] = v.x; }
}

// batch is SORTED -> segment boundaries via adjacent compare; zero atomics.
__global__ void k_bounds(const int* __restrict__ batch, int* __restrict__ bstart,
                         int* __restrict__ bend) {
  int i = blockIdx.x * 256 + threadIdx.x;
  if (i >= NN) return;
  int b = batch[i];
  if (i == 0 || batch[i - 1] != b) bstart[b] = i;
  if (i == NN - 1 || batch[i + 1] != b) bend[b] = i + 1;
}

// ---------------- matmul: out[r][c] = dis[r] * sum_k in[r][k] W[k][c] ----------------

template <int CIN>
__global__ __launch_bounds__(256) void k_matmul_scale(
    const float* __restrict__ in, const float* __restrict__ W,
    const float* __restrict__ dis, float* __restrict__ out) {
  __shared__ float Wl[CIN * 64];
  __shared__ float xr[64 * 68];
  int t = threadIdx.x;
  for (int i = t * 4; i < CIN * 64; i += 1024)
    *(float4*)&Wl[i] = *(const float4*)&W[i];

  int base = blockIdx.x * 64;
  int rows = NN - base; if (rows > 64) rows = 64;

  int cg = t & 15, rg = t >> 4;
  int c0 = cg * 4;
  float acc[4][4] = {};

  for (int kh = 0; kh < CIN; kh += 64) {
    for (int i = t * 4; i < rows * 64; i += 1024) {
      int r = i >> 6, c = i & 63;
      *(float4*)&xr[r * 68 + c] = *(const float4*)&in[(base + r) * CIN + kh + c];
    }
    __syncthreads();
#pragma unroll
    for (int kl = 0; kl < 64; kl += 4) {
      float4 xv[4], wv[4];
#pragma unroll
      for (int j = 0; j < 4; j++) xv[j] = *(float4*)&xr[(rg * 4 + j) * 68 + kl];
#pragma unroll
      for (int kk = 0; kk < 4; kk++) wv[kk] = *(float4*)&Wl[(kh + kl + kk) * 64 + c0];
#pragma unroll
      for (int kk = 0; kk < 4; kk++) {
#pragma unroll
        for (int j = 0; j < 4; j++) {
          float xs = (&xv[j].x)[kk];
          acc[j][0] += xs * wv[kk].x;
          acc[j][1] += xs * wv[kk].y;
          acc[j][2] += xs * wv[kk].z;
          acc[j][3] += xs * wv[kk].w;
        }
      }
    }
    __syncthreads();
  }

#pragma unroll
  for (int j = 0; j < 4; j++) {
    int r = base + rg * 4 + j;
    if (r < NN) {
      float dv = dis[r];
      float4 o; o.x = acc[j][0] * dv; o.y = acc[j][1] * dv; o.z = acc[j][2] * dv; o.w = acc[j][3] * dv;
      *(float4*)&out[r * 64 + c0] = o;
    }
  }
}

// ---------------- aggregation: one wave per node, lane = channel ----------------

__global__ __launch_bounds__(256) void k_agg(
    const float* __restrict__ tp, const int* __restrict__ row_start,
    const int* __restrict__ srcs, const float* __restrict__ dis,
    const float* __restrict__ bias, float* __restrict__ out) {
  int wid = (blockIdx.x * 256 + threadIdx.x) >> 6;
  int lane = threadIdx.x & 63;
  if (wid >= NN) return;
  int s = row_start[wid], e = row_start[wid + 1];
  float a0 = 0.f, a1 = 0.f, a2 = 0.f, a3 = 0.f;
  int p = s;
  for (; p + 4 <= e; p += 4) {
    int s0 = srcs[p], s1 = srcs[p + 1], s2 = srcs[p + 2], s3 = srcs[p + 3];
    a0 += tp[s0 * 64 + lane];
    a1 += tp[s1 * 64 + lane];
    a2 += tp[s2 * 64 + lane];
    a3 += tp[s3 * 64 + lane];
  }
  for (; p < e; ++p) a0 += tp[srcs[p] * 64 + lane];
  float acc = (a0 + a1) + (a2 + a3);
  float r = acc * dis[wid] + bias[lane];
  out[wid * 64 + lane] = fmaxf(r, 0.f);
}

// ---------------- fused mean-pool + 2-layer MLP ----------------

__global__ __launch_bounds__(256) void k_pool_mlp(
    const float* __restrict__ h, const int* __restrict__ bstart, const int* __restrict__ bend,
    const float* __restrict__ Wm1, const float* __restrict__ bm1,
    const float* __restrict__ Wm2, const float* __restrict__ bm2,
    float* __restrict__ out) {
  int b = blockIdx.x;
  int t = threadIdx.x;
  int lane = t & 63, w = t >> 6;
  int s = bstart[b], e = bend[b];
  float acc = 0.f;
  for (int i = s + w; i < e; i += 4) acc += h[i * 64 + lane];
  __shared__ float sums[4][64];
  __shared__ float pooled[64];
  sums[w][lane] = acc;
  __syncthreads();
  if (t < 64) {
    float tot = sums[0][t] + sums[1][t] + sums[2][t] + sums[3][t];
    int cnt = e - s;
    pooled[t] = tot / fmaxf((float)cnt, 1.0f);
  }
  __syncthreads();
  if (t < 32) {
    float z = bm1[t];
#pragma unroll
    for (int c = 0; c < 64; c++) z += pooled[c] * Wm1[c * 32 + t];
    z = fmaxf(z, 0.f) * Wm2[t];
#pragma unroll
    for (int off = 16; off > 0; off >>= 1) z += __shfl_down(z, off, 32);
    if (t == 0) out[b] = z + bm2[0];
  }
}

// ---------------- launch ----------------

extern "C" void kernel_launch(void* const* d_in, const int* in_sizes, int n_in,
                              void* d_out, int out_size, void* d_ws, size_t ws_size,
                              hipStream_t stream) {
  const float* x   = (const float*)d_in[0];
  const int*   ei  = (const int*)d_in[1];
  const int*   bat = (const int*)d_in[2];
  const float* W0  = (const float*)d_in[3];
  const float* b0  = (const float*)d_in[4];
  const float* W1  = (const float*)d_in[5];
  const float* b1  = (const float*)d_in[6];
  const float* W2  = (const float*)d_in[7];
  const float* b2  = (const float*)d_in[8];
  const float* Wm1 = (const float*)d_in[9];
  const float* bm1 = (const float*)d_in[10];
  const float* Wm2 = (const float*)d_in[11];
  const float* bm2 = (const float*)d_in[12];
  float* out = (float*)d_out;

  char* ws = (char*)d_ws;
  size_t off = 0;
  auto alloc = [&](size_t bytes) -> void* {
    void* p = ws + off; off += (bytes + 255) & ~(size_t)255; return p;
  };
  int*   deg  = (int*)  alloc((size_t)NN * 4);
  float* dis  = (float*)alloc((size_t)NN * 4);
  int*   rs   = (int*)  alloc((size_t)(NN + 1) * 4);
  int*   cur  = (int*)  alloc((size_t)NN * 4);
  int*   srcs = (int*)  alloc((size_t)MM * 4);
  float* hA   = (float*)alloc((size_t)NN * 64 * 4);   // 25.6 MB, 256B-aligned
  float* hB   = (float*)alloc((size_t)NN * 64 * 4);   // contiguous after hA
  int*   bsum = (int*)  alloc(128 * 4);
  int*   bpre = (int*)  alloc(128 * 4);
  int*   bst  = (int*)  alloc(BB * 4);
  int*   ben  = (int*)  alloc(BB * 4);
  int*   gcnt = (int*)  alloc(NBK * 4);
  int*   curB = (int*)  alloc(NBK * 4);

  // bucketed (src,dst) array: 26.4 MB, aliases hA..hB region (hA/hB are only
  // written after the CSR build has fully consumed bkt).
  int2* bkt = (int2*)hA;

  const int nb = (NN + 1023) / 1024;      // 98

  k_init<<<(NN + 255) / 256, 256, 0, stream>>>(deg, bst, ben, gcnt);
  k_hist<<<NCH, 256, 0, stream>>>(ei, gcnt);
  k_bscan<<<1, 512, 0, stream>>>(gcnt, curB);
  k_scatter<<<NCH, 256, 0, stream>>>(ei, curB, bkt);
  k_count2<<<(MM + 255) / 256, 256, 0, stream>>>(bkt, deg);
  k_scan1<<<nb, 256, 0, stream>>>(deg, bsum);
  k_scan2<<<1, 64, 0, stream>>>(bsum, bpre, nb, rs);
  k_scan3<<<nb, 256, 0, stream>>>(deg, bpre, rs);
  k_dis_cursor<<<(NN + 255) / 256, 256, 0, stream>>>(deg, rs, dis, cur);
  k_fill2<<<(MM + 255) / 256, 256, 0, stream>>>(bkt, cur, srcs);
  k_bounds<<<(NN + 255) / 256, 256, 0, stream>>>(bat, bst, ben);

  const int mmgrid = (NN + 63) / 64;      // 1563

  k_matmul_scale<128><<<mmgrid, 256, 0, stream>>>(x,  W0, dis, hA);
  k_agg<<<(NN + 3) / 4, 256, 0, stream>>>(hA, rs, srcs, dis, b0, hB);

  k_matmul_scale<64><<<mmgrid, 256, 0, stream>>>(hB, W1, dis, hA);
  k_agg<<<(NN + 3) / 4, 256, 0, stream>>>(hA, rs, srcs, dis, b1, hB);

  k_matmul_scale<64><<<mmgrid, 256, 0, stream>>>(hB, W2, dis, hA);
  k_agg<<<(NN + 3) / 4, 256, 0, stream>>>(hA, rs, srcs, dis, b2, hB);

  k_pool_mlp<<<BB, 256, 0, stream>>>(hB, bst, ben, Wm1, bm1, Wm2, bm2, out);
}

// Round 7
// 834.820 us; speedup vs baseline: 1.6401x; 1.0345x over previous
//
#include <hip/hip_runtime.h>
#include <hip/hip_fp16.h>

#define NN 100000
#define EE 3200000
#define BB 128
#define MM (EE + NN)            // edges incl. self-loops
#define NBK 391                 // buckets of 256 nodes: (NN+255)/256
#define CHUNK 8192
#define NCH ((MM + CHUNK - 1) / CHUNK)   // 403

// ---------------- setup kernels ----------------

__global__ void k_init(int* __restrict__ deg, int* __restrict__ bstart, int* __restrict__ bend,
                       int* __restrict__ gcnt) {
  int i = blockIdx.x * 256 + threadIdx.x;
  if (i < NN) deg[i] = 0;
  if (i < BB) { bstart[i] = 0; bend[i] = 0; }
  if (i < NBK) gcnt[i] = 0;
}

// per-block LDS histogram of dst buckets -> global bucket counts; also per-node degree
__global__ __launch_bounds__(256) void k_hist(const int* __restrict__ ei, int* __restrict__ gcnt,
                                              int* __restrict__ deg) {
  __shared__ int lh[NBK];
  int t = threadIdx.x;
  for (int b = t; b < NBK; b += 256) lh[b] = 0;
  __syncthreads();
  int base = blockIdx.x * CHUNK;
  for (int i = t; i < CHUNK; i += 256) {
    int e = base + i; if (e >= MM) break;
    int d = (e < EE) ? ei[EE + e] : (e - EE);
    atomicAdd(&lh[d >> 8], 1);
    atomicAdd(&deg[d], 1);          // L2-resident 400KB array; cheap
  }
  __syncthreads();
  for (int b = t; b < NBK; b += 256) { int c = lh[b]; if (c) atomicAdd(&gcnt[b], c); }
}

// exclusive scan of 391 bucket counts -> bucket cursors (one 512-thread block)
__global__ void k_bscan(const int* __restrict__ gcnt, int* __restrict__ curB) {
  __shared__ int sc[512];
  int t = threadIdx.x;
  int v = (t < NBK) ? gcnt[t] : 0;
  sc[t] = v; __syncthreads();
  for (int off = 1; off < 512; off <<= 1) {
    int u = (t >= off) ? sc[t - off] : 0;
    __syncthreads();
    sc[t] += u;
    __syncthreads();
  }
  if (t < NBK) curB[t] = sc[t] - v;     // exclusive prefix
}

// scatter edges into bucket-sorted int2 array (src,dst); coalesced-ish writes
__global__ __launch_bounds__(256) void k_scatter(const int* __restrict__ ei,
                                                 int* __restrict__ curB, int2* __restrict__ bkt) {
  __shared__ int lh[NBK];
  __shared__ int lbase[NBK];
  int t = threadIdx.x;
  for (int b = t; b < NBK; b += 256) lh[b] = 0;
  __syncthreads();
  int base = blockIdx.x * CHUNK;
  for (int i = t; i < CHUNK; i += 256) {
    int e = base + i; if (e >= MM) break;
    int d = (e < EE) ? ei[EE + e] : (e - EE);
    atomicAdd(&lh[d >> 8], 1);
  }
  __syncthreads();
  for (int b = t; b < NBK; b += 256) {
    int c = lh[b];
    lbase[b] = c ? atomicAdd(&curB[b], c) : 0;
    lh[b] = 0;
  }
  __syncthreads();
  for (int i = t; i < CHUNK; i += 256) {
    int e = base + i; if (e >= MM) break;
    int s, d;
    if (e < EE) { s = ei[e]; d = ei[EE + e]; } else { s = e - EE; d = s; }
    int b = d >> 8;
    int r = atomicAdd(&lh[b], 1);
    bkt[lbase[b] + r] = make_int2(s, d);
  }
}

// ---- exclusive scan of deg -> row_start (chunk = 1024 elems / block) ----

__global__ void k_scan1(const int* __restrict__ deg, int* __restrict__ bsum) {
  int t = threadIdx.x;
  int base = blockIdx.x * 1024 + t * 4;
  int s = 0;
#pragma unroll
  for (int j = 0; j < 4; j++) { int idx = base + j; if (idx < NN) s += deg[idx]; }
  __shared__ int red[256];
  red[t] = s; __syncthreads();
  for (int off = 128; off > 0; off >>= 1) { if (t < off) red[t] += red[t + off]; __syncthreads(); }
  if (t == 0) bsum[blockIdx.x] = red[0];
}

__global__ void k_scan2(const int* __restrict__ bsum, int* __restrict__ bpre, int nb,
                        int* __restrict__ row_start) {
  if (threadIdx.x == 0 && blockIdx.x == 0) {
    int run = 0;
    for (int i = 0; i < nb; i++) { bpre[i] = run; run += bsum[i]; }
    row_start[NN] = run;  // == MM
  }
}

__global__ void k_scan3(const int* __restrict__ deg, const int* __restrict__ bpre,
                        int* __restrict__ row_start) {
  int t = threadIdx.x;
  int base = blockIdx.x * 1024 + t * 4;
  int v[4]; int local = 0;
#pragma unroll
  for (int j = 0; j < 4; j++) { int idx = base + j; v[j] = (idx < NN) ? deg[idx] : 0; local += v[j]; }
  __shared__ int tmp[256];
  tmp[t] = local; __syncthreads();
  for (int off = 1; off < 256; off <<= 1) {
    int u = (t >= off) ? tmp[t - off] : 0;
    __syncthreads();
    tmp[t] += u;
    __syncthreads();
  }
  int run = bpre[blockIdx.x] + tmp[t] - local;
#pragma unroll
  for (int j = 0; j < 4; j++) { int idx = base + j; if (idx < NN) { row_start[idx] = run; run += v[j]; } }
}

__global__ void k_dis_cursor(const int* __restrict__ deg, const int* __restrict__ row_start,
                             float* __restrict__ dis, int* __restrict__ cursor) {
  int i = blockIdx.x * 256 + threadIdx.x;
  if (i < NN) { dis[i] = rsqrtf((float)deg[i]); cursor[i] = row_start[i]; }
}

// fill CSR srcs from bucketed stream (writes localized to ~33KB windows)
__global__ void k_fill2(const int2* __restrict__ bkt, int* __restrict__ cursor,
                        int* __restrict__ srcs) {
  int i = blockIdx.x * 256 + threadIdx.x;
  if (i < MM) { int2 v = bkt[i]; int pos = atomicAdd(&cursor[v.y], 1); srcs[pos] = v.x; }
}

// batch is SORTED -> segment boundaries via adjacent compare; zero atomics.
__global__ void k_bounds(const int* __restrict__ batch, int* __restrict__ bstart,
                         int* __restrict__ bend) {
  int i = blockIdx.x * 256 + threadIdx.x;
  if (i >= NN) return;
  int b = batch[i];
  if (i == 0 || batch[i - 1] != b) bstart[b] = i;
  if (i == NN - 1 || batch[i + 1] != b) bend[b] = i + 1;
}

// ---------------- matmul: tp[r][c] = fp16( dis[r] * sum_k in[r][k] W[k][c] ) ----------------

template <int CIN>
__global__ __launch_bounds__(256) void k_matmul_scale(
    const float* __restrict__ in, const float* __restrict__ W,
    const float* __restrict__ dis, ushort* __restrict__ out) {
  __shared__ float Wl[CIN * 64];
  __shared__ float xr[64 * 68];
  int t = threadIdx.x;
  for (int i = t * 4; i < CIN * 64; i += 1024)
    *(float4*)&Wl[i] = *(const float4*)&W[i];

  int base = blockIdx.x * 64;
  int rows = NN - base; if (rows > 64) rows = 64;

  int cg = t & 15, rg = t >> 4;
  int c0 = cg * 4;
  float acc[4][4] = {};

  for (int kh = 0; kh < CIN; kh += 64) {
    for (int i = t * 4; i < rows * 64; i += 1024) {
      int r = i >> 6, c = i & 63;
      *(float4*)&xr[r * 68 + c] = *(const float4*)&in[(base + r) * CIN + kh + c];
    }
    __syncthreads();
#pragma unroll
    for (int kl = 0; kl < 64; kl += 4) {
      float4 xv[4], wv[4];
#pragma unroll
      for (int j = 0; j < 4; j++) xv[j] = *(float4*)&xr[(rg * 4 + j) * 68 + kl];
#pragma unroll
      for (int kk = 0; kk < 4; kk++) wv[kk] = *(float4*)&Wl[(kh + kl + kk) * 64 + c0];
#pragma unroll
      for (int kk = 0; kk < 4; kk++) {
#pragma unroll
        for (int j = 0; j < 4; j++) {
          float xs = (&xv[j].x)[kk];
          acc[j][0] += xs * wv[kk].x;
          acc[j][1] += xs * wv[kk].y;
          acc[j][2] += xs * wv[kk].z;
          acc[j][3] += xs * wv[kk].w;
        }
      }
    }
    __syncthreads();
  }

#pragma unroll
  for (int j = 0; j < 4; j++) {
    int r = base + rg * 4 + j;
    if (r < NN) {
      float dv = dis[r];
      ushort4 o;
      o.x = __half_as_ushort(__float2half_rn(acc[j][0] * dv));
      o.y = __half_as_ushort(__float2half_rn(acc[j][1] * dv));
      o.z = __half_as_ushort(__float2half_rn(acc[j][2] * dv));
      o.w = __half_as_ushort(__float2half_rn(acc[j][3] * dv));
      *(ushort4*)&out[r * 64 + c0] = o;
    }
  }
}

// ---------------- aggregation: one wave per node, lane = channel ----------------
// h[i][lane] = relu(dis[i] * sum_{e in CSR(i)} fp16 tp[src_e][lane] + bias[lane]), fp32 out

__global__ __launch_bounds__(256) void k_agg(
    const ushort* __restrict__ tp, const int* __restrict__ row_start,
    const int* __restrict__ srcs, const float* __restrict__ dis,
    const float* __restrict__ bias, float* __restrict__ out) {
  int wid = (blockIdx.x * 256 + threadIdx.x) >> 6;
  int lane = threadIdx.x & 63;
  if (wid >= NN) return;
  int s = row_start[wid], e = row_start[wid + 1];
  float a0 = 0.f, a1 = 0.f, a2 = 0.f, a3 = 0.f;
  float a4 = 0.f, a5 = 0.f, a6 = 0.f, a7 = 0.f;
  int p = s;
  for (; p + 8 <= e; p += 8) {
    int i0 = srcs[p],     i1 = srcs[p + 1], i2 = srcs[p + 2], i3 = srcs[p + 3];
    int i4 = srcs[p + 4], i5 = srcs[p + 5], i6 = srcs[p + 6], i7 = srcs[p + 7];
    a0 += __half2float(__ushort_as_half(tp[i0 * 64 + lane]));
    a1 += __half2float(__ushort_as_half(tp[i1 * 64 + lane]));
    a2 += __half2float(__ushort_as_half(tp[i2 * 64 + lane]));
    a3 += __half2float(__ushort_as_half(tp[i3 * 64 + lane]));
    a4 += __half2float(__ushort_as_half(tp[i4 * 64 + lane]));
    a5 += __half2float(__ushort_as_half(tp[i5 * 64 + lane]));
    a6 += __half2float(__ushort_as_half(tp[i6 * 64 + lane]));
    a7 += __half2float(__ushort_as_half(tp[i7 * 64 + lane]));
  }
  for (; p < e; ++p) a0 += __half2float(__ushort_as_half(tp[srcs[p] * 64 + lane]));
  float acc = ((a0 + a1) + (a2 + a3)) + ((a4 + a5) + (a6 + a7));
  float r = acc * dis[wid] + bias[lane];
  out[wid * 64 + lane] = fmaxf(r, 0.f);
}

// ---------------- fused mean-pool + 2-layer MLP ----------------

__global__ __launch_bounds__(256) void k_pool_mlp(
    const float* __restrict__ h, const int* __restrict__ bstart, const int* __restrict__ bend,
    const float* __restrict__ Wm1, const float* __restrict__ bm1,
    const float* __restrict__ Wm2, const float* __restrict__ bm2,
    float* __restrict__ out) {
  int b = blockIdx.x;
  int t = threadIdx.x;
  int lane = t & 63, w = t >> 6;
  int s = bstart[b], e = bend[b];
  float acc = 0.f;
  for (int i = s + w; i < e; i += 4) acc += h[i * 64 + lane];
  __shared__ float sums[4][64];
  __shared__ float pooled[64];
  sums[w][lane] = acc;
  __syncthreads();
  if (t < 64) {
    float tot = sums[0][t] + sums[1][t] + sums[2][t] + sums[3][t];
    int cnt = e - s;
    pooled[t] = tot / fmaxf((float)cnt, 1.0f);
  }
  __syncthreads();
  if (t < 32) {
    float z = bm1[t];
#pragma unroll
    for (int c = 0; c < 64; c++) z += pooled[c] * Wm1[c * 32 + t];
    z = fmaxf(z, 0.f) * Wm2[t];
#pragma unroll
    for (int off = 16; off > 0; off >>= 1) z += __shfl_down(z, off, 32);
    if (t == 0) out[b] = z + bm2[0];
  }
}

// ---------------- launch ----------------

extern "C" void kernel_launch(void* const* d_in, const int* in_sizes, int n_in,
                              void* d_out, int out_size, void* d_ws, size_t ws_size,
                              hipStream_t stream) {
  const float* x   = (const float*)d_in[0];
  const int*   ei  = (const int*)d_in[1];
  const int*   bat = (const int*)d_in[2];
  const float* W0  = (const float*)d_in[3];
  const float* b0  = (const float*)d_in[4];
  const float* W1  = (const float*)d_in[5];
  const float* b1  = (const float*)d_in[6];
  const float* W2  = (const float*)d_in[7];
  const float* b2  = (const float*)d_in[8];
  const float* Wm1 = (const float*)d_in[9];
  const float* bm1 = (const float*)d_in[10];
  const float* Wm2 = (const float*)d_in[11];
  const float* bm2 = (const float*)d_in[12];
  float* out = (float*)d_out;

  char* ws = (char*)d_ws;
  size_t off = 0;
  auto alloc = [&](size_t bytes) -> void* {
    void* p = ws + off; off += (bytes + 255) & ~(size_t)255; return p;
  };
  int*    deg  = (int*)   alloc((size_t)NN * 4);
  float*  dis  = (float*) alloc((size_t)NN * 4);
  int*    rs   = (int*)   alloc((size_t)(NN + 1) * 4);
  int*    cur  = (int*)   alloc((size_t)NN * 4);
  int*    srcs = (int*)   alloc((size_t)MM * 4);
  // region shared by bkt (int2, 26.4 MB, CSR build only) and h (fp32, 25.6 MB, after build)
  void*   regA = alloc((size_t)MM * 8);
  ushort* tp   = (ushort*)alloc((size_t)NN * 64 * 2);   // fp16 gather table
  int*    bsum = (int*)   alloc(128 * 4);
  int*    bpre = (int*)   alloc(128 * 4);
  int*    bst  = (int*)   alloc(BB * 4);
  int*    ben  = (int*)   alloc(BB * 4);
  int*    gcnt = (int*)   alloc(NBK * 4);
  int*    curB = (int*)   alloc(NBK * 4);

  int2*  bkt = (int2*)regA;
  float* h   = (float*)regA;

  const int nb = (NN + 1023) / 1024;      // 98

  k_init<<<(NN + 255) / 256, 256, 0, stream>>>(deg, bst, ben, gcnt);
  k_hist<<<NCH, 256, 0, stream>>>(ei, gcnt, deg);
  k_bscan<<<1, 512, 0, stream>>>(gcnt, curB);
  k_scatter<<<NCH, 256, 0, stream>>>(ei, curB, bkt);
  k_scan1<<<nb, 256, 0, stream>>>(deg, bsum);
  k_scan2<<<1, 64, 0, stream>>>(bsum, bpre, nb, rs);
  k_scan3<<<nb, 256, 0, stream>>>(deg, bpre, rs);
  k_dis_cursor<<<(NN + 255) / 256, 256, 0, stream>>>(deg, rs, dis, cur);
  k_fill2<<<(MM + 255) / 256, 256, 0, stream>>>(bkt, cur, srcs);
  k_bounds<<<(NN + 255) / 256, 256, 0, stream>>>(bat, bst, ben);

  const int mmgrid = (NN + 63) / 64;      // 1563

  k_matmul_scale<128><<<mmgrid, 256, 0, stream>>>(x, W0, dis, tp);
  k_agg<<<(NN + 3) / 4, 256, 0, stream>>>(tp, rs, srcs, dis, b0, h);

  k_matmul_scale<64><<<mmgrid, 256, 0, stream>>>(h, W1, dis, tp);
  k_agg<<<(NN + 3) / 4, 256, 0, stream>>>(tp, rs, srcs, dis, b1, h);

  k_matmul_scale<64><<<mmgrid, 256, 0, stream>>>(h, W2, dis, tp);
  k_agg<<<(NN + 3) / 4, 256, 0, stream>>>(tp, rs, srcs, dis, b2, h);

  k_pool_mlp<<<BB, 256, 0, stream>>>(h, bst, ben, Wm1, bm1, Wm2, bm2, out);
}

// Round 8
// 648.494 us; speedup vs baseline: 2.1113x; 1.2873x over previous
//
#include <hip/hip_runtime.h>
#include <hip/hip_fp16.h>

#define NN 100000
#define EE 3200000
#define BB 128
#define MM (EE + NN)            // edges incl. self-loops
#define NBK 391                 // buckets of 256 nodes: (NN+255)/256
#define CHUNK 8192
#define NCH ((MM + CHUNK - 1) / CHUNK)   // 403

// ---------------- setup kernels ----------------

__global__ void k_init(int* __restrict__ bstart, int* __restrict__ bend,
                       int* __restrict__ gcnt) {
  int i = blockIdx.x * 256 + threadIdx.x;
  if (i < BB) { bstart[i] = 0; bend[i] = 0; }
  if (i < NBK) gcnt[i] = 0;
}

// per-block LDS histogram of dst buckets -> global bucket counts (NO per-node atomics)
__global__ __launch_bounds__(256) void k_hist(const int* __restrict__ ei, int* __restrict__ gcnt) {
  __shared__ int lh[NBK];
  int t = threadIdx.x;
  for (int b = t; b < NBK; b += 256) lh[b] = 0;
  __syncthreads();
  int base = blockIdx.x * CHUNK;
  for (int i = t; i < CHUNK; i += 256) {
    int e = base + i; if (e >= MM) break;
    int d = (e < EE) ? ei[EE + e] : (e - EE);
    atomicAdd(&lh[d >> 8], 1);
  }
  __syncthreads();
  for (int b = t; b < NBK; b += 256) { int c = lh[b]; if (c) atomicAdd(&gcnt[b], c); }
}

// exclusive scan of bucket counts -> scatter cursors + immutable bucket offsets; rs[NN]=MM
__global__ void k_bscan(const int* __restrict__ gcnt, int* __restrict__ curB,
                        int* __restrict__ bktoff, int* __restrict__ rs) {
  __shared__ int sc[512];
  int t = threadIdx.x;
  int v = (t < NBK) ? gcnt[t] : 0;
  sc[t] = v; __syncthreads();
  for (int off = 1; off < 512; off <<= 1) {
    int u = (t >= off) ? sc[t - off] : 0;
    __syncthreads();
    sc[t] += u;
    __syncthreads();
  }
  int ex = sc[t] - v;                  // exclusive prefix (v=0 for t>=NBK)
  if (t < NBK) curB[t] = ex;
  if (t <= NBK) bktoff[t] = ex;        // bktoff[NBK] == MM
  if (t == 0) rs[NN] = MM;
}

// scatter edges into bucket-sorted int2 array (src,dst); coalesced-ish writes
__global__ __launch_bounds__(256) void k_scatter(const int* __restrict__ ei,
                                                 int* __restrict__ curB, int2* __restrict__ bkt) {
  __shared__ int lh[NBK];
  __shared__ int lbase[NBK];
  int t = threadIdx.x;
  for (int b = t; b < NBK; b += 256) lh[b] = 0;
  __syncthreads();
  int base = blockIdx.x * CHUNK;
  for (int i = t; i < CHUNK; i += 256) {
    int e = base + i; if (e >= MM) break;
    int d = (e < EE) ? ei[EE + e] : (e - EE);
    atomicAdd(&lh[d >> 8], 1);
  }
  __syncthreads();
  for (int b = t; b < NBK; b += 256) {
    int c = lh[b];
    lbase[b] = c ? atomicAdd(&curB[b], c) : 0;
    lh[b] = 0;
  }
  __syncthreads();
  for (int i = t; i < CHUNK; i += 256) {
    int e = base + i; if (e >= MM) break;
    int s, d;
    if (e < EE) { s = ei[e]; d = ei[EE + e]; } else { s = e - EE; d = s; }
    int b = d >> 8;
    int r = atomicAdd(&lh[b], 1);
    bkt[lbase[b] + r] = make_int2(s, d);
  }
}

// per-bucket: count (LDS) -> scan (LDS) -> rs/dis -> fill srcs (LDS cursors).
// CSR row order == bucket order, so rs[node] = bktoff[b] + within-bucket prefix.
// Zero global atomics; bkt reads contiguous; srcs writes localized to the bucket window.
__global__ __launch_bounds__(256) void k_bucket(const int2* __restrict__ bkt,
                                                const int* __restrict__ bktoff,
                                                float* __restrict__ dis, int* __restrict__ rs,
                                                int* __restrict__ srcs) {
  int b = blockIdx.x, t = threadIdx.x;
  int start = bktoff[b], end = bktoff[b + 1];
  int nbase = b << 8;
  __shared__ int cnt[256];
  __shared__ int scn[256];
  __shared__ int curs[256];
  cnt[t] = 0;
  __syncthreads();
  for (int i = start + t; i < end; i += 256)
    atomicAdd(&cnt[bkt[i].y - nbase], 1);
  __syncthreads();
  int v = cnt[t];
  scn[t] = v; __syncthreads();
  for (int off = 1; off < 256; off <<= 1) {
    int u = (t >= off) ? scn[t - off] : 0;
    __syncthreads();
    scn[t] += u;
    __syncthreads();
  }
  int excl = scn[t] - v;
  int node = nbase + t;
  if (node < NN) {
    rs[node] = start + excl;
    dis[node] = rsqrtf((float)v);      // v >= 1 for all real nodes (self-loop)
  }
  curs[t] = start + excl;
  __syncthreads();
  for (int i = start + t; i < end; i += 256) {
    int2 e = bkt[i];
    int pos = atomicAdd(&curs[e.y - nbase], 1);
    srcs[pos] = e.x;
  }
}

// batch is SORTED -> segment boundaries via adjacent compare; zero atomics.
__global__ void k_bounds(const int* __restrict__ batch, int* __restrict__ bstart,
                         int* __restrict__ bend) {
  int i = blockIdx.x * 256 + threadIdx.x;
  if (i >= NN) return;
  int b = batch[i];
  if (i == 0 || batch[i - 1] != b) bstart[b] = i;
  if (i == NN - 1 || batch[i + 1] != b) bend[b] = i + 1;
}

// ---------------- matmul: tp[r][c] = fp16( dis[r] * sum_k in[r][k] W[k][c] ) ----------------

template <int CIN>
__global__ __launch_bounds__(256) void k_matmul_scale(
    const float* __restrict__ in, const float* __restrict__ W,
    const float* __restrict__ dis, ushort* __restrict__ out) {
  __shared__ float Wl[CIN * 64];
  __shared__ float xr[64 * 68];
  int t = threadIdx.x;
  for (int i = t * 4; i < CIN * 64; i += 1024)
    *(float4*)&Wl[i] = *(const float4*)&W[i];

  int base = blockIdx.x * 64;
  int rows = NN - base; if (rows > 64) rows = 64;

  int cg = t & 15, rg = t >> 4;
  int c0 = cg * 4;
  float acc[4][4] = {};

  for (int kh = 0; kh < CIN; kh += 64) {
    for (int i = t * 4; i < rows * 64; i += 1024) {
      int r = i >> 6, c = i & 63;
      *(float4*)&xr[r * 68 + c] = *(const float4*)&in[(base + r) * CIN + kh + c];
    }
    __syncthreads();
#pragma unroll
    for (int kl = 0; kl < 64; kl += 4) {
      float4 xv[4], wv[4];
#pragma unroll
      for (int j = 0; j < 4; j++) xv[j] = *(float4*)&xr[(rg * 4 + j) * 68 + kl];
#pragma unroll
      for (int kk = 0; kk < 4; kk++) wv[kk] = *(float4*)&Wl[(kh + kl + kk) * 64 + c0];
#pragma unroll
      for (int kk = 0; kk < 4; kk++) {
#pragma unroll
        for (int j = 0; j < 4; j++) {
          float xs = (&xv[j].x)[kk];
          acc[j][0] += xs * wv[kk].x;
          acc[j][1] += xs * wv[kk].y;
          acc[j][2] += xs * wv[kk].z;
          acc[j][3] += xs * wv[kk].w;
        }
      }
    }
    __syncthreads();
  }

#pragma unroll
  for (int j = 0; j < 4; j++) {
    int r = base + rg * 4 + j;
    if (r < NN) {
      float dv = dis[r];
      ushort4 o;
      o.x = __half_as_ushort(__float2half_rn(acc[j][0] * dv));
      o.y = __half_as_ushort(__float2half_rn(acc[j][1] * dv));
      o.z = __half_as_ushort(__float2half_rn(acc[j][2] * dv));
      o.w = __half_as_ushort(__float2half_rn(acc[j][3] * dv));
      *(ushort4*)&out[r * 64 + c0] = o;
    }
  }
}

// ---------------- aggregation: one wave per node, lane = channel ----------------
// h[i][lane] = relu(dis[i] * sum_{e in CSR(i)} fp16 tp[src_e][lane] + bias[lane]), fp32 out

__global__ __launch_bounds__(256) void k_agg(
    const ushort* __restrict__ tp, const int* __restrict__ row_start,
    const int* __restrict__ srcs, const float* __restrict__ dis,
    const float* __restrict__ bias, float* __restrict__ out) {
  int wid = (blockIdx.x * 256 + threadIdx.x) >> 6;
  int lane = threadIdx.x & 63;
  if (wid >= NN) return;
  int s = row_start[wid], e = row_start[wid + 1];
  float a0 = 0.f, a1 = 0.f, a2 = 0.f, a3 = 0.f;
  float a4 = 0.f, a5 = 0.f, a6 = 0.f, a7 = 0.f;
  int p = s;
  for (; p + 8 <= e; p += 8) {
    int i0 = srcs[p],     i1 = srcs[p + 1], i2 = srcs[p + 2], i3 = srcs[p + 3];
    int i4 = srcs[p + 4], i5 = srcs[p + 5], i6 = srcs[p + 6], i7 = srcs[p + 7];
    a0 += __half2float(__ushort_as_half(tp[i0 * 64 + lane]));
    a1 += __half2float(__ushort_as_half(tp[i1 * 64 + lane]));
    a2 += __half2float(__ushort_as_half(tp[i2 * 64 + lane]));
    a3 += __half2float(__ushort_as_half(tp[i3 * 64 + lane]));
    a4 += __half2float(__ushort_as_half(tp[i4 * 64 + lane]));
    a5 += __half2float(__ushort_as_half(tp[i5 * 64 + lane]));
    a6 += __half2float(__ushort_as_half(tp[i6 * 64 + lane]));
    a7 += __half2float(__ushort_as_half(tp[i7 * 64 + lane]));
  }
  for (; p < e; ++p) a0 += __half2float(__ushort_as_half(tp[srcs[p] * 64 + lane]));
  float acc = ((a0 + a1) + (a2 + a3)) + ((a4 + a5) + (a6 + a7));
  float r = acc * dis[wid] + bias[lane];
  out[wid * 64 + lane] = fmaxf(r, 0.f);
}

// ---------------- fused mean-pool + 2-layer MLP ----------------

__global__ __launch_bounds__(256) void k_pool_mlp(
    const float* __restrict__ h, const int* __restrict__ bstart, const int* __restrict__ bend,
    const float* __restrict__ Wm1, const float* __restrict__ bm1,
    const float* __restrict__ Wm2, const float* __restrict__ bm2,
    float* __restrict__ out) {
  int b = blockIdx.x;
  int t = threadIdx.x;
  int lane = t & 63, w = t >> 6;
  int s = bstart[b], e = bend[b];
  float acc = 0.f;
  for (int i = s + w; i < e; i += 4) acc += h[i * 64 + lane];
  __shared__ float sums[4][64];
  __shared__ float pooled[64];
  sums[w][lane] = acc;
  __syncthreads();
  if (t < 64) {
    float tot = sums[0][t] + sums[1][t] + sums[2][t] + sums[3][t];
    int cnt = e - s;
    pooled[t] = tot / fmaxf((float)cnt, 1.0f);
  }
  __syncthreads();
  if (t < 32) {
    float z = bm1[t];
#pragma unroll
    for (int c = 0; c < 64; c++) z += pooled[c] * Wm1[c * 32 + t];
    z = fmaxf(z, 0.f) * Wm2[t];
#pragma unroll
    for (int off = 16; off > 0; off >>= 1) z += __shfl_down(z, off, 32);
    if (t == 0) out[b] = z + bm2[0];
  }
}

// ---------------- launch ----------------

extern "C" void kernel_launch(void* const* d_in, const int* in_sizes, int n_in,
                              void* d_out, int out_size, void* d_ws, size_t ws_size,
                              hipStream_t stream) {
  const float* x   = (const float*)d_in[0];
  const int*   ei  = (const int*)d_in[1];
  const int*   bat = (const int*)d_in[2];
  const float* W0  = (const float*)d_in[3];
  const float* b0  = (const float*)d_in[4];
  const float* W1  = (const float*)d_in[5];
  const float* b1  = (const float*)d_in[6];
  const float* W2  = (const float*)d_in[7];
  const float* b2  = (const float*)d_in[8];
  const float* Wm1 = (const float*)d_in[9];
  const float* bm1 = (const float*)d_in[10];
  const float* Wm2 = (const float*)d_in[11];
  const float* bm2 = (const float*)d_in[12];
  float* out = (float*)d_out;

  char* ws = (char*)d_ws;
  size_t off = 0;
  auto alloc = [&](size_t bytes) -> void* {
    void* p = ws + off; off += (bytes + 255) & ~(size_t)255; return p;
  };
  float*  dis    = (float*) alloc((size_t)NN * 4);
  int*    rs     = (int*)   alloc((size_t)(NN + 1) * 4);
  int*    srcs   = (int*)   alloc((size_t)MM * 4);
  // region shared by bkt (int2, 26.4 MB, CSR build only) and h (fp32, 25.6 MB, after build)
  void*   regA   = alloc((size_t)MM * 8);
  ushort* tp     = (ushort*)alloc((size_t)NN * 64 * 2);   // fp16 gather table
  int*    bst    = (int*)   alloc(BB * 4);
  int*    ben    = (int*)   alloc(BB * 4);
  int*    gcnt   = (int*)   alloc(NBK * 4);
  int*    curB   = (int*)   alloc(NBK * 4);
  int*    bktoff = (int*)   alloc((NBK + 1) * 4);

  int2*  bkt = (int2*)regA;
  float* h   = (float*)regA;

  k_init<<<2, 256, 0, stream>>>(bst, ben, gcnt);
  k_hist<<<NCH, 256, 0, stream>>>(ei, gcnt);
  k_bscan<<<1, 512, 0, stream>>>(gcnt, curB, bktoff, rs);
  k_scatter<<<NCH, 256, 0, stream>>>(ei, curB, bkt);
  k_bucket<<<NBK, 256, 0, stream>>>(bkt, bktoff, dis, rs, srcs);
  k_bounds<<<(NN + 255) / 256, 256, 0, stream>>>(bat, bst, ben);

  const int mmgrid = (NN + 63) / 64;      // 1563

  k_matmul_scale<128><<<mmgrid, 256, 0, stream>>>(x, W0, dis, tp);
  k_agg<<<(NN + 3) / 4, 256, 0, stream>>>(tp, rs, srcs, dis, b0, h);

  k_matmul_scale<64><<<mmgrid, 256, 0, stream>>>(h, W1, dis, tp);
  k_agg<<<(NN + 3) / 4, 256, 0, stream>>>(tp, rs, srcs, dis, b1, h);

  k_matmul_scale<64><<<mmgrid, 256, 0, stream>>>(h, W2, dis, tp);
  k_agg<<<(NN + 3) / 4, 256, 0, stream>>>(tp, rs, srcs, dis, b2, h);

  k_pool_mlp<<<BB, 256, 0, stream>>>(h, bst, ben, Wm1, bm1, Wm2, bm2, out);
}

// Round 9
// 607.103 us; speedup vs baseline: 2.2553x; 1.0682x over previous
//
#include <hip/hip_runtime.h>
#include <hip/hip_fp16.h>

#define NN 100000
#define EE 3200000
#define BB 128
#define MM (EE + NN)            // edges incl. self-loops
#define NBK 391                 // buckets of 256 nodes: (NN+255)/256
#define CHUNK 8192
#define NCH ((MM + CHUNK - 1) / CHUNK)   // 403

// ---------------- setup kernels ----------------

__global__ void k_init(int* __restrict__ bstart, int* __restrict__ bend,
                       int* __restrict__ gcnt) {
  int i = blockIdx.x * 256 + threadIdx.x;
  if (i < BB) { bstart[i] = 0; bend[i] = 0; }
  if (i < NBK) gcnt[i] = 0;
}

// per-block LDS histogram of dst buckets -> global bucket counts (NO per-node atomics)
__global__ __launch_bounds__(256) void k_hist(const int* __restrict__ ei, int* __restrict__ gcnt) {
  __shared__ int lh[NBK];
  int t = threadIdx.x;
  for (int b = t; b < NBK; b += 256) lh[b] = 0;
  __syncthreads();
  int base = blockIdx.x * CHUNK;
  for (int i = t; i < CHUNK; i += 256) {
    int e = base + i; if (e >= MM) break;
    int d = (e < EE) ? ei[EE + e] : (e - EE);
    atomicAdd(&lh[d >> 8], 1);
  }
  __syncthreads();
  for (int b = t; b < NBK; b += 256) { int c = lh[b]; if (c) atomicAdd(&gcnt[b], c); }
}

// exclusive scan of bucket counts -> scatter cursors + immutable bucket offsets; rs[NN]=MM
__global__ void k_bscan(const int* __restrict__ gcnt, int* __restrict__ curB,
                        int* __restrict__ bktoff, int* __restrict__ rs) {
  __shared__ int sc[512];
  int t = threadIdx.x;
  int v = (t < NBK) ? gcnt[t] : 0;
  sc[t] = v; __syncthreads();
  for (int off = 1; off < 512; off <<= 1) {
    int u = (t >= off) ? sc[t - off] : 0;
    __syncthreads();
    sc[t] += u;
    __syncthreads();
  }
  int ex = sc[t] - v;                  // exclusive prefix (v=0 for t>=NBK)
  if (t < NBK) curB[t] = ex;
  if (t <= NBK) bktoff[t] = ex;        // bktoff[NBK] == MM
  if (t == 0) rs[NN] = MM;
}

// scatter edges into bucket-sorted PACKED array: (src<<8)|local_dst  (src<2^17, dl<256)
__global__ __launch_bounds__(256) void k_scatter(const int* __restrict__ ei,
                                                 int* __restrict__ curB, int* __restrict__ bkt) {
  __shared__ int lh[NBK];
  __shared__ int lbase[NBK];
  int t = threadIdx.x;
  for (int b = t; b < NBK; b += 256) lh[b] = 0;
  __syncthreads();
  int base = blockIdx.x * CHUNK;
  for (int i = t; i < CHUNK; i += 256) {
    int e = base + i; if (e >= MM) break;
    int d = (e < EE) ? ei[EE + e] : (e - EE);
    atomicAdd(&lh[d >> 8], 1);
  }
  __syncthreads();
  for (int b = t; b < NBK; b += 256) {
    int c = lh[b];
    lbase[b] = c ? atomicAdd(&curB[b], c) : 0;
    lh[b] = 0;
  }
  __syncthreads();
  for (int i = t; i < CHUNK; i += 256) {
    int e = base + i; if (e >= MM) break;
    int s, d;
    if (e < EE) { s = ei[e]; d = ei[EE + e]; } else { s = e - EE; d = s; }
    int b = d >> 8;
    int r = atomicAdd(&lh[b], 1);
    bkt[lbase[b] + r] = (s << 8) | (d & 255);
  }
}

// per-bucket: count (LDS) -> scan (LDS) -> rs/dis -> fill srcs (LDS cursors).
// CSR row order == bucket order, so rs[node] = bktoff[b] + within-bucket prefix.
__global__ __launch_bounds__(256) void k_bucket(const int* __restrict__ bkt,
                                                const int* __restrict__ bktoff,
                                                float* __restrict__ dis, int* __restrict__ rs,
                                                int* __restrict__ srcs) {
  int b = blockIdx.x, t = threadIdx.x;
  int start = bktoff[b], end = bktoff[b + 1];
  int nbase = b << 8;
  __shared__ int cnt[256];
  __shared__ int scn[256];
  __shared__ int curs[256];
  cnt[t] = 0;
  __syncthreads();
  for (int i = start + t; i < end; i += 256)
    atomicAdd(&cnt[bkt[i] & 255], 1);
  __syncthreads();
  int v = cnt[t];
  scn[t] = v; __syncthreads();
  for (int off = 1; off < 256; off <<= 1) {
    int u = (t >= off) ? scn[t - off] : 0;
    __syncthreads();
    scn[t] += u;
    __syncthreads();
  }
  int excl = scn[t] - v;
  int node = nbase + t;
  if (node < NN) {
    rs[node] = start + excl;
    dis[node] = rsqrtf((float)v);      // v >= 1 for all real nodes (self-loop)
  }
  curs[t] = start + excl;
  __syncthreads();
  for (int i = start + t; i < end; i += 256) {
    int e = bkt[i];
    int pos = atomicAdd(&curs[e & 255], 1);
    srcs[pos] = ((unsigned)e) >> 8;
  }
}

// batch is SORTED -> segment boundaries via adjacent compare; zero atomics.
__global__ void k_bounds(const int* __restrict__ batch, int* __restrict__ bstart,
                         int* __restrict__ bend) {
  int i = blockIdx.x * 256 + threadIdx.x;
  if (i >= NN) return;
  int b = batch[i];
  if (i == 0 || batch[i - 1] != b) bstart[b] = i;
  if (i == NN - 1 || batch[i + 1] != b) bend[b] = i + 1;
}

// ---------------- matmul: tp[r][c] = fp16( dis[r] * sum_k in[r][k] W[k][c] ) ----------------

template <int CIN>
__global__ __launch_bounds__(256) void k_matmul_scale(
    const float* __restrict__ in, const float* __restrict__ W,
    const float* __restrict__ dis, ushort* __restrict__ out) {
  __shared__ float Wl[CIN * 64];
  __shared__ float xr[64 * 68];
  int t = threadIdx.x;
  for (int i = t * 4; i < CIN * 64; i += 1024)
    *(float4*)&Wl[i] = *(const float4*)&W[i];

  int base = blockIdx.x * 64;
  int rows = NN - base; if (rows > 64) rows = 64;

  int cg = t & 15, rg = t >> 4;
  int c0 = cg * 4;
  float acc[4][4] = {};

  for (int kh = 0; kh < CIN; kh += 64) {
    for (int i = t * 4; i < rows * 64; i += 1024) {
      int r = i >> 6, c = i & 63;
      *(float4*)&xr[r * 68 + c] = *(const float4*)&in[(base + r) * CIN + kh + c];
    }
    __syncthreads();
#pragma unroll
    for (int kl = 0; kl < 64; kl += 4) {
      float4 xv[4], wv[4];
#pragma unroll
      for (int j = 0; j < 4; j++) xv[j] = *(float4*)&xr[(rg * 4 + j) * 68 + kl];
#pragma unroll
      for (int kk = 0; kk < 4; kk++) wv[kk] = *(float4*)&Wl[(kh + kl + kk) * 64 + c0];
#pragma unroll
      for (int kk = 0; kk < 4; kk++) {
#pragma unroll
        for (int j = 0; j < 4; j++) {
          float xs = (&xv[j].x)[kk];
          acc[j][0] += xs * wv[kk].x;
          acc[j][1] += xs * wv[kk].y;
          acc[j][2] += xs * wv[kk].z;
          acc[j][3] += xs * wv[kk].w;
        }
      }
    }
    __syncthreads();
  }

#pragma unroll
  for (int j = 0; j < 4; j++) {
    int r = base + rg * 4 + j;
    if (r < NN) {
      float dv = dis[r];
      ushort4 o;
      o.x = __half_as_ushort(__float2half_rn(acc[j][0] * dv));
      o.y = __half_as_ushort(__float2half_rn(acc[j][1] * dv));
      o.z = __half_as_ushort(__float2half_rn(acc[j][2] * dv));
      o.w = __half_as_ushort(__float2half_rn(acc[j][3] * dv));
      *(ushort4*)&out[r * 64 + c0] = o;
    }
  }
}

// ---------------- aggregation: one wave per node; pair-packed channels ----------------
// lane handles channels {2c, 2c+1} (c = lane&31) of row-half (lane>>5).
// One uint load = 2 fp16 channels; one VMEM instruction fetches TWO edge rows
// (lanes 0-31 -> edge 2j, lanes 32-63 -> edge 2j+1). Cross-half combine via shfl_xor(32).

__global__ __launch_bounds__(256) void k_agg(
    const ushort* __restrict__ tp, const int* __restrict__ row_start,
    const int* __restrict__ srcs, const float* __restrict__ dis,
    const float* __restrict__ bias, float* __restrict__ out) {
  int wid = (blockIdx.x * 256 + threadIdx.x) >> 6;
  int lane = threadIdx.x & 63;
  if (wid >= NN) return;
  int s = row_start[wid], e = row_start[wid + 1];
  int half = lane >> 5;
  int cp = lane & 31;                   // channel pair index
  float ax[8] = {}, ay[8] = {};

  int p = s;
  for (; p + 16 <= e; p += 16) {
    int idx = srcs[p + (lane & 15)];    // one coalesced load of 16 indices
#pragma unroll
    for (int j = 0; j < 8; j++) {
      int r = __shfl(idx, 2 * j + half, 16);
      uint u = *(const uint*)(tp + (((size_t)r) << 6) + (cp << 1));
      ax[j] += __half2float(__ushort_as_half((ushort)(u & 0xffff)));
      ay[j] += __half2float(__ushort_as_half((ushort)(u >> 16)));
    }
  }
  for (; p + 2 <= e; p += 2) {          // pair tail
    int r = srcs[p + half];
    uint u = *(const uint*)(tp + (((size_t)r) << 6) + (cp << 1));
    ax[0] += __half2float(__ushort_as_half((ushort)(u & 0xffff)));
    ay[0] += __half2float(__ushort_as_half((ushort)(u >> 16)));
  }
  if (p < e && half == 0) {             // last odd edge: half 0 only
    int r = srcs[p];
    uint u = *(const uint*)(tp + (((size_t)r) << 6) + (cp << 1));
    ax[0] += __half2float(__ushort_as_half((ushort)(u & 0xffff)));
    ay[0] += __half2float(__ushort_as_half((ushort)(u >> 16)));
  }

  float sx = ((ax[0] + ax[1]) + (ax[2] + ax[3])) + ((ax[4] + ax[5]) + (ax[6] + ax[7]));
  float sy = ((ay[0] + ay[1]) + (ay[2] + ay[3])) + ((ay[4] + ay[5]) + (ay[6] + ay[7]));
  sx += __shfl_xor(sx, 32);
  sy += __shfl_xor(sy, 32);

  if (half == 0) {
    float dv = dis[wid];
    float2 bv = *(const float2*)&bias[cp * 2];
    float2 o;
    o.x = fmaxf(sx * dv + bv.x, 0.f);
    o.y = fmaxf(sy * dv + bv.y, 0.f);
    *(float2*)&out[wid * 64 + cp * 2] = o;
  }
}

// ---------------- fused mean-pool + 2-layer MLP ----------------

__global__ __launch_bounds__(256) void k_pool_mlp(
    const float* __restrict__ h, const int* __restrict__ bstart, const int* __restrict__ bend,
    const float* __restrict__ Wm1, const float* __restrict__ bm1,
    const float* __restrict__ Wm2, const float* __restrict__ bm2,
    float* __restrict__ out) {
  int b = blockIdx.x;
  int t = threadIdx.x;
  int lane = t & 63, w = t >> 6;
  int s = bstart[b], e = bend[b];
  float acc = 0.f;
  for (int i = s + w; i < e; i += 4) acc += h[i * 64 + lane];
  __shared__ float sums[4][64];
  __shared__ float pooled[64];
  sums[w][lane] = acc;
  __syncthreads();
  if (t < 64) {
    float tot = sums[0][t] + sums[1][t] + sums[2][t] + sums[3][t];
    int cnt = e - s;
    pooled[t] = tot / fmaxf((float)cnt, 1.0f);
  }
  __syncthreads();
  if (t < 32) {
    float z = bm1[t];
#pragma unroll
    for (int c = 0; c < 64; c++) z += pooled[c] * Wm1[c * 32 + t];
    z = fmaxf(z, 0.f) * Wm2[t];
#pragma unroll
    for (int off = 16; off > 0; off >>= 1) z += __shfl_down(z, off, 32);
    if (t == 0) out[b] = z + bm2[0];
  }
}

// ---------------- launch ----------------

extern "C" void kernel_launch(void* const* d_in, const int* in_sizes, int n_in,
                              void* d_out, int out_size, void* d_ws, size_t ws_size,
                              hipStream_t stream) {
  const float* x   = (const float*)d_in[0];
  const int*   ei  = (const int*)d_in[1];
  const int*   bat = (const int*)d_in[2];
  const float* W0  = (const float*)d_in[3];
  const float* b0  = (const float*)d_in[4];
  const float* W1  = (const float*)d_in[5];
  const float* b1  = (const float*)d_in[6];
  const float* W2  = (const float*)d_in[7];
  const float* b2  = (const float*)d_in[8];
  const float* Wm1 = (const float*)d_in[9];
  const float* bm1 = (const float*)d_in[10];
  const float* Wm2 = (const float*)d_in[11];
  const float* bm2 = (const float*)d_in[12];
  float* out = (float*)d_out;

  char* ws = (char*)d_ws;
  size_t off = 0;
  auto alloc = [&](size_t bytes) -> void* {
    void* p = ws + off; off += (bytes + 255) & ~(size_t)255; return p;
  };
  float*  dis    = (float*) alloc((size_t)NN * 4);
  int*    rs     = (int*)   alloc((size_t)(NN + 1) * 4);
  int*    srcs   = (int*)   alloc((size_t)MM * 4);
  // region shared by bkt (packed int, 13.2 MB, CSR build only) and h (fp32, 25.6 MB, after)
  void*   regA   = alloc((size_t)MM * 8);
  ushort* tp     = (ushort*)alloc((size_t)NN * 64 * 2);   // fp16 gather table
  int*    bst    = (int*)   alloc(BB * 4);
  int*    ben    = (int*)   alloc(BB * 4);
  int*    gcnt   = (int*)   alloc(NBK * 4);
  int*    curB   = (int*)   alloc(NBK * 4);
  int*    bktoff = (int*)   alloc((NBK + 1) * 4);

  int*   bkt = (int*)regA;
  float* h   = (float*)regA;

  k_init<<<2, 256, 0, stream>>>(bst, ben, gcnt);
  k_hist<<<NCH, 256, 0, stream>>>(ei, gcnt);
  k_bscan<<<1, 512, 0, stream>>>(gcnt, curB, bktoff, rs);
  k_scatter<<<NCH, 256, 0, stream>>>(ei, curB, bkt);
  k_bucket<<<NBK, 256, 0, stream>>>(bkt, bktoff, dis, rs, srcs);
  k_bounds<<<(NN + 255) / 256, 256, 0, stream>>>(bat, bst, ben);

  const int mmgrid = (NN + 63) / 64;      // 1563

  k_matmul_scale<128><<<mmgrid, 256, 0, stream>>>(x, W0, dis, tp);
  k_agg<<<(NN + 3) / 4, 256, 0, stream>>>(tp, rs, srcs, dis, b0, h);

  k_matmul_scale<64><<<mmgrid, 256, 0, stream>>>(h, W1, dis, tp);
  k_agg<<<(NN + 3) / 4, 256, 0, stream>>>(tp, rs, srcs, dis, b1, h);

  k_matmul_scale<64><<<mmgrid, 256, 0, stream>>>(h, W2, dis, tp);
  k_agg<<<(NN + 3) / 4, 256, 0, stream>>>(tp, rs, srcs, dis, b2, h);

  k_pool_mlp<<<BB, 256, 0, stream>>>(h, bst, ben, Wm1, bm1, Wm2, bm2, out);
}